// Round 4
// baseline (267.276 us; speedup 1.0000x reference)
//
#include <hip/hip_runtime.h>

typedef __attribute__((ext_vector_type(8))) short s16x8;
typedef __attribute__((ext_vector_type(8))) unsigned short u16x8;
typedef __attribute__((ext_vector_type(4))) float f32x4;
typedef unsigned short u16;
typedef unsigned int u32;

#define T_ 2048
#define C_ 512
#define H_ 8
#define DKP 96
#define LOG2E 1.44269504088896340736f
#define QSCALE 0.18033688011112042f  // 0.125 * log2(e)

__device__ __forceinline__ u16 f2b(float f) {
  u32 u = __float_as_uint(f);
  return (u16)((u + 0x7FFFu + ((u >> 16) & 1u)) >> 16);
}

__device__ __forceinline__ float b2f(u16 b) {
  return __uint_as_float(((u32)b) << 16);
}

__device__ __forceinline__ u32 cvtpk(float a, float b) {
  u32 d;
  asm("v_cvt_pk_bf16_f32 %0, %1, %2" : "=v"(d) : "v"(a), "v"(b));
  return d;
}

__device__ __forceinline__ u16x8 cvt8(float4 a, float4 b) {
  u16x8 o;
  o[0] = f2b(a.x); o[1] = f2b(a.y); o[2] = f2b(a.z); o[3] = f2b(a.w);
  o[4] = f2b(b.x); o[5] = f2b(b.y); o[6] = f2b(b.z); o[7] = f2b(b.w);
  return o;
}

__device__ __forceinline__ f32x4 mfma16(s16x8 a, s16x8 b, f32x4 c) {
  return __builtin_amdgcn_mfma_f32_16x16x32_bf16(a, b, c, 0, 0, 0);
}

// global -> LDS DMA, 16B per lane; LDS dest must be wave-uniform base + lane*16
#define GLL(gp, lp) __builtin_amdgcn_global_load_lds( \
    (const __attribute__((address_space(1))) unsigned int*)(gp), \
    (__attribute__((address_space(3))) unsigned int*)(lp), 16, 0, 0)

// ---------------------------------------------------------------------------
// Convert/pack: xb, Wcat(Wq|Wk|Wv), Wo16, bcat(fp32), Q pad cols (onehot q%3),
// K pad cols (bias[c][k%3] * log2e).
// ---------------------------------------------------------------------------
__global__ __launch_bounds__(256) void k_convert(
    const float* __restrict__ x,
    const float* __restrict__ wq, const float* __restrict__ wk,
    const float* __restrict__ wv, const float* __restrict__ wo,
    const float* __restrict__ bq, const float* __restrict__ bk,
    const float* __restrict__ bv, const float* __restrict__ pb,
    u16* __restrict__ xb, u16* __restrict__ wcat, u16* __restrict__ wo16,
    float* __restrict__ bcat, u16* __restrict__ qp, u16* __restrict__ kp)
{
  const int blk = blockIdx.x, tid = threadIdx.x;
  if (blk < 2048) {
    int i = blk * 2048 + tid * 8;
    float4 a = *(const float4*)(x + i);
    float4 b = *(const float4*)(x + i + 4);
    *(u16x8*)(xb + i) = cvt8(a, b);
  } else if (blk < 2432) {
    int bi = blk - 2048;
    const float* src; int off;
    if (bi < 128)      { src = wq; off = bi * 2048; }
    else if (bi < 256) { src = wk; off = (bi - 128) * 2048; }
    else               { src = wv; off = (bi - 256) * 2048; }
    int i = off + tid * 8;
    float4 a = *(const float4*)(src + i);
    float4 b = *(const float4*)(src + i + 4);
    *(u16x8*)(wcat + bi * 2048 + tid * 8) = cvt8(a, b);
  } else if (blk < 2560) {
    int i = (blk - 2432) * 2048 + tid * 8;
    float4 a = *(const float4*)(wo + i);
    float4 b = *(const float4*)(wo + i + 4);
    *(u16x8*)(wo16 + i) = cvt8(a, b);
  } else if (blk == 2560) {
    if (tid < 192) {
      int i = tid * 8;
      const float* src; int off;
      if (i < 512)       { src = bq; off = i; }
      else if (i < 1024) { src = bk; off = i - 512; }
      else               { src = bv; off = i - 1024; }
      *(float4*)(bcat + i)     = *(const float4*)(src + off);
      *(float4*)(bcat + i + 4) = *(const float4*)(src + off + 4);
    }
  } else if (blk < 3585) {
    int e = (blk - 2561) * 2048 + tid * 8;
    int row = e >> 5, cc = e & 31;
    int tp = (row & 2047) % 3;
    u16x8 o;
    #pragma unroll
    for (int j = 0; j < 8; ++j) {
      int cidx = cc + j;
      o[j] = (cidx < 3) ? ((tp == cidx) ? (u16)0x3F80 : (u16)0) : (u16)0;
    }
    *(u16x8*)(qp + row * DKP + 64 + cc) = o;
  } else {
    int e = (blk - 3585) * 2048 + tid * 8;
    int row = e >> 5, cc = e & 31;
    int tp = (row & 2047) % 3;
    u16x8 o;
    #pragma unroll
    for (int j = 0; j < 8; ++j) {
      int cidx = cc + j;
      o[j] = (cidx < 3) ? f2b(pb[cidx * 3 + tp] * LOG2E) : (u16)0;
    }
    *(u16x8*)(kp + row * DKP + 64 + cc) = o;
  }
}

// ---------------------------------------------------------------------------
// GEMM  C[m][n] = A[m][:] . B[n][:] + bias[n]   (A,B bf16 K-contig, K=512)
// m97 structure: global_load_lds width-16 into linear LDS [128][32], BK=32,
// 2 barriers/iter. 4 waves (2x2), each 64x64 via 4x4 frags of 16x16x32.
// MODE 0: QKV — Qp scaled 0.125*log2e, Kp, Vtmp.   MODE 1: O-proj fp32.
// ---------------------------------------------------------------------------
template<int MODE>
__global__ __launch_bounds__(256) void k_gemm(
    const u16* __restrict__ A, const u16* __restrict__ Bw,
    const float* __restrict__ bias,
    u16* __restrict__ qp, u16* __restrict__ kp, u16* __restrict__ vtmp,
    float* __restrict__ yout)
{
  const int n0 = blockIdx.x * 128;
  const int m0 = blockIdx.y * 128;
  const int tid = threadIdx.x;
  const int lane = tid & 63, wid = tid >> 6;
  const int g = lane >> 4, c = lane & 15;
  const int wm = wid >> 1, wn = wid & 1;

  __shared__ alignas(16) u16 As[128 * 32];
  __shared__ alignas(16) u16 Bs[128 * 32];

  f32x4 acc[4][4];
  #pragma unroll
  for (int i = 0; i < 4; ++i)
    #pragma unroll
    for (int j = 0; j < 4; ++j) acc[i][j] = f32x4{0.f, 0.f, 0.f, 0.f};

  const u16* Ag0 = A + (m0 + (tid >> 2)) * C_ + (tid & 3) * 8;
  const u16* Ag1 = Ag0 + 64 * C_;
  const u16* Bg0 = Bw + (n0 + (tid >> 2)) * C_ + (tid & 3) * 8;
  const u16* Bg1 = Bg0 + 64 * C_;
  u16* Al0 = As + tid * 8;
  u16* Al1 = As + (256 + tid) * 8;
  u16* Bl0 = Bs + tid * 8;
  u16* Bl1 = Bs + (256 + tid) * 8;

  const int KT = C_ / 32;
  for (int kt = 0; kt < KT; ++kt) {
    GLL(Ag0 + kt * 32, Al0);
    GLL(Ag1 + kt * 32, Al1);
    GLL(Bg0 + kt * 32, Bl0);
    GLL(Bg1 + kt * 32, Bl1);
    __syncthreads();          // drains vmcnt -> tile staged
    s16x8 af[4], bf[4];
    #pragma unroll
    for (int mf = 0; mf < 4; ++mf)
      af[mf] = *(const s16x8*)(As + (wm * 64 + mf * 16 + c) * 32 + g * 8);
    #pragma unroll
    for (int nf = 0; nf < 4; ++nf)
      bf[nf] = *(const s16x8*)(Bs + (wn * 64 + nf * 16 + c) * 32 + g * 8);
    #pragma unroll
    for (int mf = 0; mf < 4; ++mf)
      #pragma unroll
      for (int nf = 0; nf < 4; ++nf)
        acc[mf][nf] = mfma16(af[mf], bf[nf], acc[mf][nf]);
    __syncthreads();          // all reads done before next overwrite
  }

  float bv4[4];
  #pragma unroll
  for (int nf = 0; nf < 4; ++nf) bv4[nf] = bias[n0 + wn * 64 + nf * 16 + c];

  #pragma unroll
  for (int mf = 0; mf < 4; ++mf) {
    const int btb = m0 + wm * 64 + mf * 16 + g * 4;
    #pragma unroll
    for (int nf = 0; nf < 4; ++nf) {
      const int n = n0 + wn * 64 + nf * 16 + c;
      #pragma unroll
      for (int r = 0; r < 4; ++r) {
        float v = acc[mf][nf][r] + bv4[nf];
        const int row = btb + r;
        if (MODE == 1) {
          yout[row * C_ + n] = v;
        } else {
          if (n < 512) {
            const int hh = n >> 6, d = n & 63;
            const int bb = row >> 11, t = row & 2047;
            qp[((bb * H_ + hh) * T_ + t) * DKP + d] = f2b(v * QSCALE);
          } else if (n < 1024) {
            const int nn = n - 512;
            const int hh = nn >> 6, d = nn & 63;
            const int bb = row >> 11, t = row & 2047;
            kp[((bb * H_ + hh) * T_ + t) * DKP + d] = f2b(v);
          } else {
            vtmp[row * C_ + (n - 1024)] = f2b(v);
          }
        }
      }
    }
  }
}

// ---------------------------------------------------------------------------
// V transpose: Vtmp[bt][c] -> Vt[bh][80][T] with keys PERMUTED within each
// 32-group: key k -> 2*(k&15) + (k>>4)  (matches attn's packed-P col order).
// Row 64 = ones (softmax-l), rows 65..79 = zeros (perm-invariant).
// ---------------------------------------------------------------------------
__global__ __launch_bounds__(256) void k_vtrans(const u16* __restrict__ vtmp,
                                                u16* __restrict__ vt)
{
  const int t0 = blockIdx.x * 64;
  const int bh = blockIdx.y;
  const int b = bh >> 3, h = bh & 7;
  const int tid = threadIdx.x;
  __shared__ alignas(16) u16 tile[64 * 72];
  #pragma unroll
  for (int it = 0; it < 2; ++it) {
    int task = tid + it * 256;
    int r = task >> 3, cj = task & 7;
    int pr = (r & 32) | (((r & 15) << 1) | ((r >> 4) & 1));
    u16x8 v = *(const u16x8*)(vtmp + (b * T_ + t0 + r) * C_ + h * 64 + cj * 8);
    #pragma unroll
    for (int j = 0; j < 8; ++j) tile[(cj * 8 + j) * 72 + pr] = v[j];
  }
  __syncthreads();
  #pragma unroll
  for (int it = 0; it < 2; ++it) {
    int task = tid + it * 256;
    int d = task >> 3, cj = task & 7;
    u16x8 o = *(const u16x8*)(tile + d * 72 + cj * 8);
    *(u16x8*)(vt + (bh * 80 + d) * T_ + t0 + cj * 8) = o;
  }
  if (tid < 128) {
    int d = 64 + (tid >> 3), cj = tid & 7;
    u16 val = (d == 64) ? (u16)0x3F80 : (u16)0;
    u16x8 o;
    #pragma unroll
    for (int j = 0; j < 8; ++j) o[j] = val;
    *(u16x8*)(vt + (bh * 80 + d) * T_ + t0 + cj * 8) = o;
  }
}

// ---------------------------------------------------------------------------
// Flash attention, fixed-max softmax, NO K/V LDS staging: B-fragments are read
// directly from global (L2/L1-resident panels: 192KB K + 160KB V per bh-z,
// ~2.8MB per XCD under the swizzle). No __syncthreads in the loop; only the
// per-wave P tile goes through LDS (lgkmcnt-ordered within the wave).
// Grid: 1024 blocks -> (bh, z, qblk), XCD-grouped. KV-split z in {0,1}.
// ---------------------------------------------------------------------------
__global__ __launch_bounds__(256) void k_attn(
    const u16* __restrict__ qp, const u16* __restrict__ kp,
    const u16* __restrict__ vt, u16* __restrict__ pc0, u16* __restrict__ pc1,
    float* __restrict__ pl)
{
  const int lid = blockIdx.x;
  const int xcd = lid & 7, j = lid >> 3;
  const int gsel = j >> 4, qblk = j & 15;
  const int bhz = xcd * 8 + gsel;
  const int bh = bhz >> 1, z = bhz & 1;

  const int tid = threadIdx.x, wid = tid >> 6, lane = tid & 63;
  const int g = lane >> 4, c = lane & 15;

  __shared__ alignas(16) u16 Ps[4][32 * 40];  // per-wave P tile only

  const int q0 = qblk * 128 + wid * 32;
  const u16* qpb = qp + (bh * T_ + q0) * DKP;
  s16x8 qfr[2][3];
  #pragma unroll
  for (int a = 0; a < 2; ++a)
    #pragma unroll
    for (int ks = 0; ks < 3; ++ks)
      qfr[a][ks] = *(const s16x8*)(qpb + (a * 16 + c) * DKP + ks * 32 + g * 8);

  f32x4 acc[2][5];
  #pragma unroll
  for (int a = 0; a < 2; ++a)
    #pragma unroll
    for (int df = 0; df < 5; ++df) acc[a][df] = f32x4{0.f, 0.f, 0.f, 0.f};

  const u16* kpt = kp + ((size_t)bh * T_ + z * 1024) * DKP;
  const u16* vpt = vt + (size_t)bh * 80 * T_ + z * 1024;

  for (int kt = 0; kt < 32; ++kt) {
    const u16* kb = kpt + kt * (32 * DKP);
    const u16* vb = vpt + kt * 32;

    // QK^T (phase bias + log2e scaling baked into Qp/Kp), K-frags from L2/L1
    f32x4 s2[2][2];
    #pragma unroll
    for (int a = 0; a < 2; ++a)
      #pragma unroll
      for (int kf = 0; kf < 2; ++kf) s2[a][kf] = f32x4{0.f, 0.f, 0.f, 0.f};
    #pragma unroll
    for (int kf = 0; kf < 2; ++kf)
      #pragma unroll
      for (int ks = 0; ks < 3; ++ks) {
        s16x8 kfrag = *(const s16x8*)(kb + (kf * 16 + c) * DKP + ks * 32 + g * 8);
        s2[0][kf] = mfma16(qfr[0][ks], kfrag, s2[0][kf]);
        s2[1][kf] = mfma16(qfr[1][ks], kfrag, s2[1][kf]);
      }

    // fixed-max softmax: p = 2^s; cvt_pk packs (kf0,kf1) -> one u32
    // (interleaved key order matches permuted V rows)
    #pragma unroll
    for (int a = 0; a < 2; ++a) {
      u32* pw = (u32*)(Ps[wid] + (a * 16 + g * 4) * 40) + c;
      #pragma unroll
      for (int r = 0; r < 4; ++r) {
        float e0 = __builtin_amdgcn_exp2f(s2[a][0][r]);
        float e1 = __builtin_amdgcn_exp2f(s2[a][1][r]);
        pw[r * 20] = cvtpk(e0, e1);
      }
    }

    // PV (+ l via ones row of Vt), V-frags from L2/L1
    s16x8 pf0 = *(const s16x8*)(Ps[wid] + c * 40 + g * 8);
    s16x8 pf1 = *(const s16x8*)(Ps[wid] + (16 + c) * 40 + g * 8);
    #pragma unroll
    for (int df = 0; df < 5; ++df) {
      s16x8 vfrag = *(const s16x8*)(vb + (df * 16 + c) * T_ + g * 8);
      acc[0][df] = mfma16(pf0, vfrag, acc[0][df]);
      acc[1][df] = mfma16(pf1, vfrag, acc[1][df]);
    }
  }

  // store unnormalized partials: ctx bf16 [bh][t][64] per split, l fp32
  u16* pcz = z ? pc1 : pc0;
  float* plz = pl + z * 65536;
  #pragma unroll
  for (int a = 0; a < 2; ++a) {
    #pragma unroll
    for (int r = 0; r < 4; ++r) {
      const int trow = q0 + a * 16 + g * 4 + r;
      u16* outp = pcz + ((size_t)bh * T_ + trow) * 64;
      #pragma unroll
      for (int df = 0; df < 4; ++df)
        outp[df * 16 + c] = f2b(acc[a][df][r]);
      if (c == 0) plz[bh * T_ + trow] = acc[a][4][r];
    }
  }
}

// ---------------------------------------------------------------------------
// Combine KV-split partials: ctx = (c0+c1)/(l0+l1), write bf16 [b][t][h*64+d]
// ---------------------------------------------------------------------------
__global__ __launch_bounds__(256) void k_combine(
    const u16* __restrict__ pc0, const u16* __restrict__ pc1,
    const float* __restrict__ pl, u16* __restrict__ ctxb)
{
  const int gid = blockIdx.x * 256 + threadIdx.x;
  const int row = gid >> 3;            // bh*2048 + t
  const int dj = (gid & 7) * 8;
  const u16x8 c0 = *(const u16x8*)(pc0 + (size_t)row * 64 + dj);
  const u16x8 c1 = *(const u16x8*)(pc1 + (size_t)row * 64 + dj);
  const float inv = 1.0f / (pl[row] + pl[65536 + row]);
  u16x8 o;
  #pragma unroll
  for (int j = 0; j < 8; ++j)
    o[j] = f2b((b2f(c0[j]) + b2f(c1[j])) * inv);
  const int bh = row >> 11, t = row & 2047;
  const int b = bh >> 3, h = bh & 7;
  *(u16x8*)(ctxb + ((size_t)(b * T_ + t)) * C_ + h * 64 + dj) = o;
}

// ---------------------------------------------------------------------------
// Residual + LayerNorm
// ---------------------------------------------------------------------------
__global__ __launch_bounds__(256) void k_ln(
    const float* __restrict__ yo, const float* __restrict__ x,
    const float* __restrict__ gg, const float* __restrict__ bb,
    float* __restrict__ out)
{
  const int row = blockIdx.x * 4 + (threadIdx.x >> 6);
  const int lane = threadIdx.x & 63;
  const float4* yp = (const float4*)(yo + row * C_);
  const float4* xp = (const float4*)(x + row * C_);
  float4 v[2];
  float s = 0.f, ss = 0.f;
  #pragma unroll
  for (int i = 0; i < 2; ++i) {
    float4 a = yp[lane * 2 + i];
    float4 xx = xp[lane * 2 + i];
    float4 w;
    w.x = a.x + xx.x; w.y = a.y + xx.y; w.z = a.z + xx.z; w.w = a.w + xx.w;
    v[i] = w;
    s += w.x + w.y + w.z + w.w;
    ss += w.x * w.x + w.y * w.y + w.z * w.z + w.w * w.w;
  }
  #pragma unroll
  for (int m = 1; m < 64; m <<= 1) {
    s += __shfl_xor(s, m);
    ss += __shfl_xor(ss, m);
  }
  const float mu = s * (1.0f / 512.0f);
  const float rs = rsqrtf(ss * (1.0f / 512.0f) - mu * mu + 1e-5f);
  const float4* gp = (const float4*)gg;
  const float4* bp = (const float4*)bb;
  float4* op = (float4*)(out + row * C_);
  #pragma unroll
  for (int i = 0; i < 2; ++i) {
    float4 gv = gp[lane * 2 + i], bv = bp[lane * 2 + i];
    float4 w = v[i], o;
    o.x = (w.x - mu) * rs * gv.x + bv.x;
    o.y = (w.y - mu) * rs * gv.y + bv.y;
    o.z = (w.z - mu) * rs * gv.z + bv.z;
    o.w = (w.w - mu) * rs * gv.w + bv.w;
    op[lane * 2 + i] = o;
  }
}

// ---------------------------------------------------------------------------
extern "C" void kernel_launch(void* const* d_in, const int* in_sizes, int n_in,
                              void* d_out, int out_size, void* d_ws, size_t ws_size,
                              hipStream_t stream)
{
  const float* x   = (const float*)d_in[0];
  const float* wqw = (const float*)d_in[1];
  const float* wqb = (const float*)d_in[2];
  const float* wkw = (const float*)d_in[3];
  const float* wkb = (const float*)d_in[4];
  const float* wvw = (const float*)d_in[5];
  const float* wvb = (const float*)d_in[6];
  const float* wow = (const float*)d_in[7];
  const float* wob = (const float*)d_in[8];
  const float* pb  = (const float*)d_in[9];
  const float* lng = (const float*)d_in[10];
  const float* lnb = (const float*)d_in[11];

  char* w = (char*)d_ws;
  u16*   xb   = (u16*)(w + 0);            //  8.39 MB  -> reused as pc0 (z=0)
  u16*   wcat = (u16*)(w + 8388608);      //  1.57 MB  -> reused as pl (0.52 MB)
  u16*   wo16 = (u16*)(w + 9961472);      //  0.52 MB  (live until k_gemm<1>)
  float* bcat = (float*)(w + 10485760);   //  6 KB
  u16*   qp   = (u16*)(w + 10491904);     // 12.58 MB  [bh][t][96]
  u16*   kp   = (u16*)(w + 23074816);     // 12.58 MB
  u16*   vtmp = (u16*)(w + 35657728);     //  8.39 MB  -> reused as pc1 (z=1)
  u16*   vtq  = (u16*)(w + 44046336);     // 10.49 MB  [bh][80][2048] (perm keys)
  u16*   ctxb = (u16*)(w + 54532096);     //  8.39 MB  (end 62.9 MB)
  float* yout = (float*)(w + 10491904);   // 16.78 MB, aliases qp/kp (dead then)
  u16*   pc0  = xb;                       // partial ctx split 0
  u16*   pc1  = vtmp;                     // partial ctx split 1
  float* pl   = (float*)wcat;             // partial l: 2 x 65536 f32

  k_convert<<<4609, 256, 0, stream>>>(x, wqw, wkw, wvw, wow, wqb, wkb, wvb, pb,
                                      xb, wcat, wo16, bcat, qp, kp);
  k_gemm<0><<<dim3(12, 64), 256, 0, stream>>>(xb, wcat, bcat, qp, kp, vtmp, nullptr);
  k_vtrans<<<dim3(32, 32), 256, 0, stream>>>(vtmp, vtq);
  k_attn<<<1024, 256, 0, stream>>>(qp, kp, vtq, pc0, pc1, pl);
  k_combine<<<2048, 256, 0, stream>>>(pc0, pc1, pl, ctxb);
  k_gemm<1><<<dim3(4, 64), 256, 0, stream>>>(ctxb, wo16, wob, nullptr, nullptr, nullptr, yout);
  k_ln<<<2048, 256, 0, stream>>>(yout, x, lng, lnb, (float*)d_out);
}

// Round 5
// 201.296 us; speedup vs baseline: 1.3278x; 1.3278x over previous
//
#include <hip/hip_runtime.h>

typedef __attribute__((ext_vector_type(8))) short s16x8;
typedef __attribute__((ext_vector_type(8))) unsigned short u16x8;
typedef __attribute__((ext_vector_type(4))) float f32x4;
typedef unsigned short u16;
typedef unsigned int u32;

#define T_ 2048
#define C_ 512
#define H_ 8
#define DKP 128   // padded head dim: 64 data + 32 bias-trick + 32 pad (pow2 chunks)
#define LOG2E 1.44269504088896340736f
#define QSCALE 0.18033688011112042f  // 0.125 * log2(e)

__device__ __forceinline__ u16 f2b(float f) {
  u32 u = __float_as_uint(f);
  return (u16)((u + 0x7FFFu + ((u >> 16) & 1u)) >> 16);
}

__device__ __forceinline__ float b2f(u16 b) {
  return __uint_as_float(((u32)b) << 16);
}

__device__ __forceinline__ u32 cvtpk(float a, float b) {
  u32 d;
  asm("v_cvt_pk_bf16_f32 %0, %1, %2" : "=v"(d) : "v"(a), "v"(b));
  return d;
}

__device__ __forceinline__ u16x8 cvt8(float4 a, float4 b) {
  u16x8 o;
  o[0] = f2b(a.x); o[1] = f2b(a.y); o[2] = f2b(a.z); o[3] = f2b(a.w);
  o[4] = f2b(b.x); o[5] = f2b(b.y); o[6] = f2b(b.z); o[7] = f2b(b.w);
  return o;
}

__device__ __forceinline__ f32x4 mfma16(s16x8 a, s16x8 b, f32x4 c) {
  return __builtin_amdgcn_mfma_f32_16x16x32_bf16(a, b, c, 0, 0, 0);
}

// global -> LDS DMA, 16B/lane; LDS dest = wave-uniform base + lane*16 (linear)
#define GLL(gp, lp) __builtin_amdgcn_global_load_lds( \
    (const __attribute__((address_space(1))) unsigned int*)(gp), \
    (__attribute__((address_space(3))) unsigned int*)(lp), 16, 0, 0)

// ---------------------------------------------------------------------------
// Convert/pack. qp/kp rows are DKP=128 u16: [0,64) data, [64,96) bias-trick
// cols, [96,128) uninitialized pad (fetched by swizzle, never read).
// ---------------------------------------------------------------------------
__global__ __launch_bounds__(256) void k_convert(
    const float* __restrict__ x,
    const float* __restrict__ wq, const float* __restrict__ wk,
    const float* __restrict__ wv, const float* __restrict__ wo,
    const float* __restrict__ bq, const float* __restrict__ bk,
    const float* __restrict__ bv, const float* __restrict__ pb,
    u16* __restrict__ xb, u16* __restrict__ wcat, u16* __restrict__ wo16,
    float* __restrict__ bcat, u16* __restrict__ qp, u16* __restrict__ kp)
{
  const int blk = blockIdx.x, tid = threadIdx.x;
  if (blk < 2048) {
    int i = blk * 2048 + tid * 8;
    float4 a = *(const float4*)(x + i);
    float4 b = *(const float4*)(x + i + 4);
    *(u16x8*)(xb + i) = cvt8(a, b);
  } else if (blk < 2432) {
    int bi = blk - 2048;
    const float* src; int off;
    if (bi < 128)      { src = wq; off = bi * 2048; }
    else if (bi < 256) { src = wk; off = (bi - 128) * 2048; }
    else               { src = wv; off = (bi - 256) * 2048; }
    int i = off + tid * 8;
    float4 a = *(const float4*)(src + i);
    float4 b = *(const float4*)(src + i + 4);
    *(u16x8*)(wcat + bi * 2048 + tid * 8) = cvt8(a, b);
  } else if (blk < 2560) {
    int i = (blk - 2432) * 2048 + tid * 8;
    float4 a = *(const float4*)(wo + i);
    float4 b = *(const float4*)(wo + i + 4);
    *(u16x8*)(wo16 + i) = cvt8(a, b);
  } else if (blk == 2560) {
    if (tid < 192) {
      int i = tid * 8;
      const float* src; int off;
      if (i < 512)       { src = bq; off = i; }
      else if (i < 1024) { src = bk; off = i - 512; }
      else               { src = bv; off = i - 1024; }
      *(float4*)(bcat + i)     = *(const float4*)(src + off);
      *(float4*)(bcat + i + 4) = *(const float4*)(src + off + 4);
    }
  } else if (blk < 3585) {
    int e = (blk - 2561) * 2048 + tid * 8;
    int row = e >> 5, cc = e & 31;
    int tp = (row & 2047) % 3;
    u16x8 o;
    #pragma unroll
    for (int j = 0; j < 8; ++j) {
      int cidx = cc + j;
      o[j] = (cidx < 3) ? ((tp == cidx) ? (u16)0x3F80 : (u16)0) : (u16)0;
    }
    *(u16x8*)(qp + row * DKP + 64 + cc) = o;
  } else {
    int e = (blk - 3585) * 2048 + tid * 8;
    int row = e >> 5, cc = e & 31;
    int tp = (row & 2047) % 3;
    u16x8 o;
    #pragma unroll
    for (int j = 0; j < 8; ++j) {
      int cidx = cc + j;
      o[j] = (cidx < 3) ? f2b(pb[cidx * 3 + tp] * LOG2E) : (u16)0;
    }
    *(u16x8*)(kp + row * DKP + 64 + cc) = o;
  }
}

// ---------------------------------------------------------------------------
// GEMM  C[m][n] = A[m][:] . B[n][:] + bias[n]  (bf16, K=512), BK=64.
// global_load_lds direct with source-swizzle: LDS [128][64] linear; involution
// col16 ^= (row&7) applied on global src AND on ds_read -> all LDS accesses
// land 2 lanes/bank (free). One tile in flight, 2 barriers/iter (m97 style).
// ---------------------------------------------------------------------------
template<int MODE>
__global__ __launch_bounds__(256, 2) void k_gemm(
    const u16* __restrict__ A, const u16* __restrict__ Bw,
    const float* __restrict__ bias,
    u16* __restrict__ qp, u16* __restrict__ kp, u16* __restrict__ vtmp,
    float* __restrict__ yout)
{
  const int n0 = blockIdx.x * 128;
  const int m0 = blockIdx.y * 128;
  const int tid = threadIdx.x;
  const int lane = tid & 63, wid = tid >> 6;
  const int g = lane >> 4, c = lane & 15;
  const int wm = wid >> 1, wn = wid & 1;

  __shared__ alignas(16) u16 As[128 * 64];
  __shared__ alignas(16) u16 Bs[128 * 64];

  f32x4 acc[4][4];
  #pragma unroll
  for (int i = 0; i < 4; ++i)
    #pragma unroll
    for (int j = 0; j < 4; ++j) acc[i][j] = f32x4{0.f, 0.f, 0.f, 0.f};

  // staging map: chunk ch = i*256+tid; row=ch>>3, col=ch&7 (8 chunks/row)
  const int KT = C_ / 64;
  for (int kt = 0; kt < KT; ++kt) {
    #pragma unroll
    for (int i = 0; i < 4; ++i) {
      int ch = i * 256 + tid;
      int row = ch >> 3, col = ch & 7;
      int gcol = (col ^ (row & 7)) << 3;
      GLL(A + (m0 + row) * C_ + kt * 64 + gcol, As + (ch << 3));
      GLL(Bw + (n0 + row) * C_ + kt * 64 + gcol, Bs + (ch << 3));
    }
    __syncthreads();   // vmcnt(0): tile staged
    #pragma unroll
    for (int ks = 0; ks < 2; ++ks) {
      s16x8 af[4], bf[4];
      #pragma unroll
      for (int mf = 0; mf < 4; ++mf) {
        int row = wm * 64 + mf * 16 + c;
        af[mf] = *(const s16x8*)(As + row * 64 + (((ks * 4 + g) ^ (c & 7)) << 3));
      }
      #pragma unroll
      for (int nf = 0; nf < 4; ++nf) {
        int row = wn * 64 + nf * 16 + c;
        bf[nf] = *(const s16x8*)(Bs + row * 64 + (((ks * 4 + g) ^ (c & 7)) << 3));
      }
      #pragma unroll
      for (int mf = 0; mf < 4; ++mf)
        #pragma unroll
        for (int nf = 0; nf < 4; ++nf)
          acc[mf][nf] = mfma16(af[mf], bf[nf], acc[mf][nf]);
    }
    __syncthreads();   // reads done before next overwrite
  }

  float bv4[4];
  #pragma unroll
  for (int nf = 0; nf < 4; ++nf) bv4[nf] = bias[n0 + wn * 64 + nf * 16 + c];

  #pragma unroll
  for (int mf = 0; mf < 4; ++mf) {
    const int btb = m0 + wm * 64 + mf * 16 + g * 4;
    #pragma unroll
    for (int nf = 0; nf < 4; ++nf) {
      const int n = n0 + wn * 64 + nf * 16 + c;
      #pragma unroll
      for (int r = 0; r < 4; ++r) {
        float v = acc[mf][nf][r] + bv4[nf];
        const int row = btb + r;
        if (MODE == 1) {
          yout[row * C_ + n] = v;
        } else {
          if (n < 512) {
            const int hh = n >> 6, d = n & 63;
            const int bb = row >> 11, t = row & 2047;
            qp[((bb * H_ + hh) * T_ + t) * DKP + d] = f2b(v * QSCALE);
          } else if (n < 1024) {
            const int nn = n - 512;
            const int hh = nn >> 6, d = nn & 63;
            const int bb = row >> 11, t = row & 2047;
            kp[((bb * H_ + hh) * T_ + t) * DKP + d] = f2b(v);
          } else {
            vtmp[row * C_ + (n - 1024)] = f2b(v);
          }
        }
      }
    }
  }
}

// ---------------------------------------------------------------------------
// V transpose: Vtmp[bt][c] -> Vt[bh][64][T] with keys PERMUTED within each
// 32-group: key k -> 2*(k&15) + (k>>4)  (matches attn's packed-P col order).
// ---------------------------------------------------------------------------
__global__ __launch_bounds__(256) void k_vtrans(const u16* __restrict__ vtmp,
                                                u16* __restrict__ vt)
{
  const int t0 = blockIdx.x * 64;
  const int bh = blockIdx.y;
  const int b = bh >> 3, h = bh & 7;
  const int tid = threadIdx.x;
  __shared__ alignas(16) u16 tile[64 * 72];
  #pragma unroll
  for (int it = 0; it < 2; ++it) {
    int task = tid + it * 256;
    int r = task >> 3, cj = task & 7;
    int pr = (r & 32) | (((r & 15) << 1) | ((r >> 4) & 1));
    u16x8 v = *(const u16x8*)(vtmp + (b * T_ + t0 + r) * C_ + h * 64 + cj * 8);
    #pragma unroll
    for (int j = 0; j < 8; ++j) tile[(cj * 8 + j) * 72 + pr] = v[j];
  }
  __syncthreads();
  #pragma unroll
  for (int it = 0; it < 2; ++it) {
    int task = tid + it * 256;
    int d = task >> 3, cj = task & 7;
    u16x8 o = *(const u16x8*)(tile + d * 72 + cj * 8);
    *(u16x8*)(vt + (bh * 64 + d) * T_ + t0 + cj * 8) = o;
  }
}

// ---------------------------------------------------------------------------
// Flash attention, fixed-max softmax. KVBLK=64, double-buffered LDS K/V staged
// via global_load_lds with source-swizzle (col16 ^= row&7), ONE barrier/iter.
// l accumulated via constant ones-fragment MFMA (col 64 of acc).
// Grid: 1024 blocks -> (bh, z, qblk), XCD-grouped; KV-split z in {0,1}.
// ---------------------------------------------------------------------------
__global__ __launch_bounds__(256, 2) void k_attn(
    const u16* __restrict__ qp, const u16* __restrict__ kp,
    const u16* __restrict__ vt, u16* __restrict__ pc0, u16* __restrict__ pc1,
    float* __restrict__ pl)
{
  const int lid = blockIdx.x;
  const int xcd = lid & 7, j = lid >> 3;
  const int gsel = j >> 4, qblk = j & 15;
  const int bhz = xcd * 8 + gsel;
  const int bh = bhz >> 1, z = bhz & 1;

  const int tid = threadIdx.x, wid = tid >> 6, lane = tid & 63;
  const int g = lane >> 4, c = lane & 15;

  // K: [64][128] u16 x2 (32 KB)  V: [64][64] u16 x2 (16 KB)  P: 4x[32][40] (10 KB)
  __shared__ alignas(16) u16 Kb[2 * 64 * 128];
  __shared__ alignas(16) u16 Vb[2 * 64 * 64];
  __shared__ alignas(16) u16 Pb[4 * 32 * 40];

  const int q0 = qblk * 128 + wid * 32;
  const u16* qpb = qp + ((size_t)bh * T_ + q0) * DKP;
  s16x8 qfr[2][3];
  #pragma unroll
  for (int a = 0; a < 2; ++a)
    #pragma unroll
    for (int ks = 0; ks < 3; ++ks)
      qfr[a][ks] = *(const s16x8*)(qpb + (a * 16 + c) * DKP + ks * 32 + g * 8);

  f32x4 acc[2][5];
  #pragma unroll
  for (int a = 0; a < 2; ++a)
    #pragma unroll
    for (int df = 0; df < 5; ++df) acc[a][df] = f32x4{0.f, 0.f, 0.f, 0.f};

  // constant B-frag for l: V-row 64 = ones, 65..79 = zeros -> lanes c==0 ones
  s16x8 lfrag;
  {
    u16 lv = (c == 0) ? (u16)0x3F80 : (u16)0;
    #pragma unroll
    for (int i = 0; i < 8; ++i) ((u16*)&lfrag)[i] = lv;
  }

  const u16* kpt = kp + ((size_t)bh * T_ + z * 1024) * DKP;
  const u16* vpt = vt + (size_t)bh * 64 * T_ + z * 1024;
  u16* Pw = Pb + wid * (32 * 40);

  // stage tile t into buffer half bsel (6 x 4KB DMA calls, source-swizzled)
  auto STAGE = [&](int t, int bsel) {
    const u16* ks0 = kpt + (size_t)t * (64 * DKP);
    u16* kd = Kb + bsel * (64 * 128);
    #pragma unroll
    for (int i = 0; i < 4; ++i) {
      int ch = i * 256 + tid;
      int row = ch >> 4, col = ch & 15;
      GLL(ks0 + row * DKP + ((col ^ (row & 7)) << 3), kd + (ch << 3));
    }
    const u16* vs0 = vpt + t * 64;
    u16* vd = Vb + bsel * (64 * 64);
    #pragma unroll
    for (int i = 0; i < 2; ++i) {
      int ch = i * 256 + tid;
      int row = ch >> 3, col = ch & 7;
      GLL(vs0 + row * T_ + ((col ^ (row & 7)) << 3), vd + (ch << 3));
    }
  };

  STAGE(0, 0);
  __syncthreads();

  for (int kt = 0; kt < 16; ++kt) {
    const int cur = kt & 1;
    if (kt < 15) STAGE(kt + 1, cur ^ 1);

    const u16* Kc = Kb + cur * (64 * 128);
    const u16* Vc = Vb + cur * (64 * 64);

    #pragma unroll
    for (int s = 0; s < 2; ++s) {
      // QK^T over 32 keys (bias + log2e baked into Qp/Kp pads)
      f32x4 s2[2][2];
      #pragma unroll
      for (int a = 0; a < 2; ++a)
        #pragma unroll
        for (int kf = 0; kf < 2; ++kf) s2[a][kf] = f32x4{0.f, 0.f, 0.f, 0.f};
      #pragma unroll
      for (int kf = 0; kf < 2; ++kf)
        #pragma unroll
        for (int ks = 0; ks < 3; ++ks) {
          int row = s * 32 + kf * 16 + c;
          s16x8 kfrag = *(const s16x8*)(Kc + row * 128 +
                                        (((ks * 4 + g) ^ (c & 7)) << 3));
          s2[0][kf] = mfma16(qfr[0][ks], kfrag, s2[0][kf]);
          s2[1][kf] = mfma16(qfr[1][ks], kfrag, s2[1][kf]);
        }

      // fixed-max softmax: p = 2^s; pack (kf0,kf1) pairs (permuted key order)
      #pragma unroll
      for (int a = 0; a < 2; ++a) {
        u32* pw = (u32*)Pw + (a * 16 + g * 4) * 20 + c;
        #pragma unroll
        for (int r = 0; r < 4; ++r) {
          float e0 = __builtin_amdgcn_exp2f(s2[a][0][r]);
          float e1 = __builtin_amdgcn_exp2f(s2[a][1][r]);
          pw[r * 20] = cvtpk(e0, e1);
        }
      }

      // PV for this 32-key sub-block (+ l via constant ones-frag)
      #pragma unroll
      for (int a = 0; a < 2; ++a) {
        s16x8 pf = *(const s16x8*)(Pw + (a * 16 + c) * 40 + g * 8);
        #pragma unroll
        for (int df = 0; df < 4; ++df) {
          int row = df * 16 + c;
          s16x8 vfrag = *(const s16x8*)(Vc + row * 64 +
                                        (((s * 4 + g) ^ (c & 7)) << 3));
          acc[a][df] = mfma16(pf, vfrag, acc[a][df]);
        }
        acc[a][4] = mfma16(pf, lfrag, acc[a][4]);
      }
    }

    if (kt < 15) __syncthreads();  // drains prefetch vmcnt + WAR protection
  }

  // store unnormalized partials: ctx bf16 [bh][t][64] per split, l fp32
  u16* pcz = z ? pc1 : pc0;
  float* plz = pl + z * 65536;
  #pragma unroll
  for (int a = 0; a < 2; ++a) {
    #pragma unroll
    for (int r = 0; r < 4; ++r) {
      const int trow = q0 + a * 16 + g * 4 + r;
      u16* outp = pcz + ((size_t)bh * T_ + trow) * 64;
      #pragma unroll
      for (int df = 0; df < 4; ++df)
        outp[df * 16 + c] = f2b(acc[a][df][r]);
      if (c == 0) plz[bh * T_ + trow] = acc[a][4][r];
    }
  }
}

// ---------------------------------------------------------------------------
// Combine KV-split partials: ctx = (c0+c1)/(l0+l1), write bf16 [b][t][h*64+d]
// ---------------------------------------------------------------------------
__global__ __launch_bounds__(256) void k_combine(
    const u16* __restrict__ pc0, const u16* __restrict__ pc1,
    const float* __restrict__ pl, u16* __restrict__ ctxb)
{
  const int gid = blockIdx.x * 256 + threadIdx.x;
  const int row = gid >> 3;            // bh*2048 + t
  const int dj = (gid & 7) * 8;
  const u16x8 c0 = *(const u16x8*)(pc0 + (size_t)row * 64 + dj);
  const u16x8 c1 = *(const u16x8*)(pc1 + (size_t)row * 64 + dj);
  const float inv = 1.0f / (pl[row] + pl[65536 + row]);
  u16x8 o;
  #pragma unroll
  for (int j = 0; j < 8; ++j)
    o[j] = f2b((b2f(c0[j]) + b2f(c1[j])) * inv);
  const int bh = row >> 11, t = row & 2047;
  const int b = bh >> 3, h = bh & 7;
  *(u16x8*)(ctxb + ((size_t)(b * T_ + t)) * C_ + h * 64 + dj) = o;
}

// ---------------------------------------------------------------------------
// Residual + LayerNorm
// ---------------------------------------------------------------------------
__global__ __launch_bounds__(256) void k_ln(
    const float* __restrict__ yo, const float* __restrict__ x,
    const float* __restrict__ gg, const float* __restrict__ bb,
    float* __restrict__ out)
{
  const int row = blockIdx.x * 4 + (threadIdx.x >> 6);
  const int lane = threadIdx.x & 63;
  const float4* yp = (const float4*)(yo + row * C_);
  const float4* xp = (const float4*)(x + row * C_);
  float4 v[2];
  float s = 0.f, ss = 0.f;
  #pragma unroll
  for (int i = 0; i < 2; ++i) {
    float4 a = yp[lane * 2 + i];
    float4 xx = xp[lane * 2 + i];
    float4 w;
    w.x = a.x + xx.x; w.y = a.y + xx.y; w.z = a.z + xx.z; w.w = a.w + xx.w;
    v[i] = w;
    s += w.x + w.y + w.z + w.w;
    ss += w.x * w.x + w.y * w.y + w.z * w.z + w.w * w.w;
  }
  #pragma unroll
  for (int m = 1; m < 64; m <<= 1) {
    s += __shfl_xor(s, m);
    ss += __shfl_xor(ss, m);
  }
  const float mu = s * (1.0f / 512.0f);
  const float rs = rsqrtf(ss * (1.0f / 512.0f) - mu * mu + 1e-5f);
  const float4* gp = (const float4*)gg;
  const float4* bp = (const float4*)bb;
  float4* op = (float4*)(out + row * C_);
  #pragma unroll
  for (int i = 0; i < 2; ++i) {
    float4 gv = gp[lane * 2 + i], bv = bp[lane * 2 + i];
    float4 w = v[i], o;
    o.x = (w.x - mu) * rs * gv.x + bv.x;
    o.y = (w.y - mu) * rs * gv.y + bv.y;
    o.z = (w.z - mu) * rs * gv.z + bv.z;
    o.w = (w.w - mu) * rs * gv.w + bv.w;
    op[lane * 2 + i] = o;
  }
}

// ---------------------------------------------------------------------------
extern "C" void kernel_launch(void* const* d_in, const int* in_sizes, int n_in,
                              void* d_out, int out_size, void* d_ws, size_t ws_size,
                              hipStream_t stream)
{
  const float* x   = (const float*)d_in[0];
  const float* wqw = (const float*)d_in[1];
  const float* wqb = (const float*)d_in[2];
  const float* wkw = (const float*)d_in[3];
  const float* wkb = (const float*)d_in[4];
  const float* wvw = (const float*)d_in[5];
  const float* wvb = (const float*)d_in[6];
  const float* wow = (const float*)d_in[7];
  const float* wob = (const float*)d_in[8];
  const float* pb  = (const float*)d_in[9];
  const float* lng = (const float*)d_in[10];
  const float* lnb = (const float*)d_in[11];

  char* w = (char*)d_ws;
  u16*   xb   = (u16*)(w + 0);            //  8.39 MB -> pc0 after gemm<0>
  u16*   wcat = (u16*)(w + 8388608);      //  1.57 MB -> pl after gemm<0>
  u16*   wo16 = (u16*)(w + 9961472);      //  0.52 MB (live until gemm<1>)
  float* bcat = (float*)(w + 10485760);   //  8 KB
  u16*   qp   = (u16*)(w + 10493952);     // 16.78 MB [bh][t][128] -> yout alias
  u16*   kp   = (u16*)(w + 27271168);     // 16.78 MB [bh][t][128] -> ctxb alias
  u16*   vtmp = (u16*)(w + 44048384);     //  8.39 MB -> pc1 after vtrans
  u16*   vtq  = (u16*)(w + 52436992);     //  8.39 MB [bh][64][2048] (perm keys)
                                          //  end 60.83 MB
  u16*   pc0  = xb;
  u16*   pc1  = vtmp;
  float* pl   = (float*)wcat;             // 2 x 65536 f32
  u16*   ctxb = kp;                       // kp dead after k_attn
  float* yout = (float*)qp;               // qp dead after k_attn

  k_convert<<<4609, 256, 0, stream>>>(x, wqw, wkw, wvw, wow, wqb, wkb, wvb, pb,
                                      xb, wcat, wo16, bcat, qp, kp);
  k_gemm<0><<<dim3(12, 64), 256, 0, stream>>>(xb, wcat, bcat, qp, kp, vtmp, nullptr);
  k_vtrans<<<dim3(32, 32), 256, 0, stream>>>(vtmp, vtq);
  k_attn<<<1024, 256, 0, stream>>>(qp, kp, vtq, pc0, pc1, pl);
  k_combine<<<2048, 256, 0, stream>>>(pc0, pc1, pl, ctxb);
  k_gemm<1><<<dim3(4, 64), 256, 0, stream>>>(ctxb, wo16, wob, nullptr, nullptr, nullptr, yout);
  k_ln<<<2048, 256, 0, stream>>>(yout, x, lng, lnb, (float*)d_out);
}